// Round 16
// baseline (140.750 us; speedup 1.0000x reference)
//
#include <hip/hip_runtime.h>
#include <hip/hip_bf16.h>

// Problem constants
//   x:   [4096, 4096] f32
//   w:   [4096, 7, 64] f32   (weight[j*64+k][a][n])
//   w1:  [64, 4096] f32      (lowrank_first)
//   w2:  [4096, 64] f32      (lowrank_second)
//   fwd: [64, 7] i32         (forward_indices; idx = j*7 + a)
//   out: [4096, 4096] f32
//
// out block p = sum_s x[:, j_s*64:+64] @ w[j_s,:,a_s,:]  +  T @ W2_p^T
// with T = x @ w1^T.  Per p: GEMM [4096,512] x [512,64].
// R16 = R13/R15 best build with reduce_t fused into compute_t via
// last-workgroup fix-up (saves one launch + gap). All GEMM kernels verbatim.

#define DEVINL __device__ __forceinline__

typedef __attribute__((ext_vector_type(8))) short bfx8;   // 8 bf16 (4 VGPRs)
typedef __attribute__((ext_vector_type(4))) float fx4;

DEVINL short f2bf(float f) {   // round-to-nearest-even f32 -> bf16 bits
  unsigned u = __builtin_bit_cast(unsigned, f);
  unsigned r = 0x7FFFu + ((u >> 16) & 1u);
  return (short)((u + r) >> 16);
}

// XOR swizzle: tiles are [rows][64 cols] bf16, row stride 128 B.
// byte offset = row*128 + (colbyte ^ ((row&7)<<4))  -> ds_read_b128 conflict-free.
DEVINL int swzb(int row, int kbyte) { return (row << 7) + (kbyte ^ ((row & 7) << 4)); }

DEVINL void gload16(const void* g, void* l) {
  __builtin_amdgcn_global_load_lds(
      (const __attribute__((address_space(1))) unsigned int*)g,
      (__attribute__((address_space(3))) unsigned int*)l, 16, 0, 0);
}

// ---------------------------------------------------------------------------
// P0 (merged): blocks 0..575 = prep_b; blocks 576..8767 = convert_x.
// (proven round-7 kernel, verbatim)
// ---------------------------------------------------------------------------
__global__ __launch_bounds__(256) void prep_all_kern(
    const float* __restrict__ weight, const float* __restrict__ w1,
    const float* __restrict__ w2, const int* __restrict__ fwd,
    const float* __restrict__ x, unsigned short* __restrict__ bmat,
    unsigned short* __restrict__ w1b, unsigned short* __restrict__ xb) {
  int cid = blockIdx.x, tid = threadIdx.x;
  if (cid >= 576) {
    int gid = (cid - 576) * 256 + tid;
    int b = gid >> 9, c8 = gid & 511;
    int j = c8 >> 3, c0 = (c8 & 7) << 3;
    const float* src = x + (size_t)b * 4096 + j * 64 + c0;
    fx4 v0 = *(const fx4*)src;
    fx4 v1 = *(const fx4*)(src + 4);
    bfx8 o;
    o[0] = f2bf(v0[0]); o[1] = f2bf(v0[1]); o[2] = f2bf(v0[2]); o[3] = f2bf(v0[3]);
    o[4] = f2bf(v1[0]); o[5] = f2bf(v1[1]); o[6] = f2bf(v1[2]); o[7] = f2bf(v1[3]);
    size_t off = (size_t)j * 262144 + (size_t)b * 64 + ((((c0 << 1) ^ ((b & 7) << 4))) >> 1);
    *(bfx8*)(xb + off) = o;
    return;
  }
  if (cid < 512) {
    int p = cid >> 3, t = cid & 7;
    unsigned short* dst = bmat + (size_t)cid * 4096;
    if (t < 7) {
      int idx = fwd[p * 7 + t];
      int j = idx / 7, a = idx - j * 7;
      int k = tid >> 2, n0 = (tid & 3) << 4;
      const float* src = weight + ((size_t)(j * 64 + k) * 7 + a) * 64 + n0;
#pragma unroll
      for (int e = 0; e < 16; ++e) {
        int n = n0 + e;
        dst[(n << 6) + ((((k << 1) ^ ((n & 7) << 4))) >> 1)] = f2bf(src[e]);
      }
    } else {
      int n = tid >> 2, r0 = (tid & 3) << 4;
      const float* src = w2 + ((size_t)(p * 64 + n)) * 64 + r0;
#pragma unroll
      for (int e = 0; e < 16; ++e) {
        int k = r0 + e;
        dst[(n << 6) + ((((k << 1) ^ ((n & 7) << 4))) >> 1)] = f2bf(src[e]);
      }
    }
  } else {
    int jc = cid - 512;
    unsigned short* dst = w1b + (size_t)jc * 4096;
    int r = tid >> 2, k0 = (tid & 3) << 4;
    const float* src = w1 + (size_t)r * 4096 + jc * 64 + k0;
#pragma unroll
    for (int e = 0; e < 16; ++e) {
      int k = k0 + e;
      dst[(r << 6) + ((((k << 1) ^ ((r & 7) << 4))) >> 1)] = f2bf(src[e]);
    }
  }
}

// ---------------------------------------------------------------------------
// P1 (fused): split-K T-partials + last-wg reduce. 512 wgs = 64 rt x 8 kc.
// GEMM body verbatim from proven compute_t_split. After writing partials,
// each wg: __threadfence(); atomicAdd(cnt[rt]); the 8th arrival re-fences
// and reduces rt's 64 rows into tb (math verbatim from proven reduce_t).
// Deterministic: sum is over fixed kc order 0..7 regardless of which wg
// performs it. cnt reset by hipMemsetAsync each launch.
// ---------------------------------------------------------------------------
__global__ __launch_bounds__(256) void compute_t_fused(const unsigned short* __restrict__ xb,
                                                       const unsigned short* __restrict__ w1b,
                                                       float* __restrict__ part,
                                                       unsigned short* __restrict__ tb,
                                                       int* __restrict__ cnt) {
  __shared__ char smem[32768];
  int rt = blockIdx.x >> 3, kc = blockIdx.x & 7;
  int tid = threadIdx.x, lane = tid & 63, w = tid >> 6;
  int lr = lane & 15, lkb = (lane >> 4) << 4;

  auto stage = [&](int jc, int buf) {
    const unsigned short* sa = xb + (size_t)(kc * 8 + jc) * 262144 + (size_t)rt * 4096;
    const unsigned short* sb = w1b + (size_t)(kc * 8 + jc) * 4096;
    char* da = smem + buf * 8192;
    char* db = smem + 16384 + buf * 8192;
#pragma unroll
    for (int i = 0; i < 2; ++i) {
      gload16(sa + tid * 8 + i * 2048, da + tid * 16 + i * 4096);
      gload16(sb + tid * 8 + i * 2048, db + tid * 16 + i * 4096);
    }
  };

  fx4 acc[4] = {};
  stage(0, 0);
#pragma unroll 1
  for (int jc = 0; jc < 8; ++jc) {
    __syncthreads();
    int cur = jc & 1;
    if (jc < 7) stage(jc + 1, cur ^ 1);
    const char* ab = smem + cur * 8192;
    const char* bb = smem + 16384 + cur * 8192;
#pragma unroll
    for (int kk = 0; kk < 2; ++kk) {
      bfx8 af = *(const bfx8*)(ab + swzb(w * 16 + lr, kk * 64 + lkb));
#pragma unroll
      for (int ni = 0; ni < 4; ++ni) {
        bfx8 bf = *(const bfx8*)(bb + swzb(ni * 16 + lr, kk * 64 + lkb));
        acc[ni] = __builtin_amdgcn_mfma_f32_16x16x32_bf16(af, bf, acc[ni], 0, 0, 0);
      }
    }
  }
  float* pb = part + (size_t)kc * 262144 + (size_t)rt * 4096;
#pragma unroll
  for (int ni = 0; ni < 4; ++ni)
#pragma unroll
    for (int r = 0; r < 4; ++r) {
      int row = w * 16 + (lane >> 4) * 4 + r;
      pb[(size_t)row * 64 + ni * 16 + lr] = acc[ni][r];
    }

  // ---- fused reduce: last wg of this rt sums the 8 partials -> tb ----
  __threadfence();                          // publish partials (device scope)
  __shared__ int lastFlag;
  if (tid == 0) lastFlag = (atomicAdd(&cnt[rt], 1) == 7) ? 1 : 0;
  __syncthreads();
  if (lastFlag) {
    __threadfence();                        // acquire: see all 8 partials
#pragma unroll
    for (int u = 0; u < 2; ++u) {
      int idx = tid * 2 + u;                // 512 units: 64 rows x 8 col-groups
      int b = rt * 64 + (idx >> 3);
      int c0 = (idx & 7) << 3;
      const float* pp = part + (size_t)b * 64 + c0;
      fx4 s0 = {0.f, 0.f, 0.f, 0.f}, s1 = {0.f, 0.f, 0.f, 0.f};
#pragma unroll
      for (int k2 = 0; k2 < 8; ++k2) {
        s0 += *(const fx4*)(pp + (size_t)k2 * 262144);
        s1 += *(const fx4*)(pp + (size_t)k2 * 262144 + 4);
      }
      bfx8 o;
#pragma unroll
      for (int e = 0; e < 4; ++e) { o[e] = f2bf(s0[e]); o[e + 4] = f2bf(s1[e]); }
      *(bfx8*)(tb + (size_t)b * 64 + ((((c0 << 1) ^ ((b & 7) << 4))) >> 1)) = o;
    }
  }
}

// ---------------------------------------------------------------------------
// P2: multi-p butterfly GEMM, 256-row tiles. (proven round-13 kernel, verbatim)
// 512 wgs = 16 mt x 32 pg (2 adjacent p per wg). 512 thr (8 waves), wave =
// 32 rows, acc[2][2][4] statically indexed. Staged 320 MB; LDS 80 KB ->
// 2 wg/CU = 16 waves/CU (measured optimum). Coarse 512B-strip epilogue.
// ---------------------------------------------------------------------------
__global__ __launch_bounds__(512, 2) void butterfly_mp5(
    const unsigned short* __restrict__ xb, const unsigned short* __restrict__ tb,
    const unsigned short* __restrict__ bmat, const int* __restrict__ fwd,
    float* __restrict__ out) {
  __shared__ char smem[81920];   // A dbuf 2x32K @0; B dbuf 2x8K @65536
  int bid = blockIdx.x;
  int wid = (bid & 7) * 64 + (bid >> 3);   // bijective XCD swizzle (512 % 8 == 0)
  int mt = wid >> 5, pg = wid & 31;        // pg fastest within an XCD chunk
  int tid = threadIdx.x, lane = tid & 63, w = tid >> 6;
  int lr = lane & 15, lkb = (lane >> 4) << 4;

  auto stage = [&](int s, int buf) {       // s = q*8 + t
    int qq = s >> 3, tt = s & 7;
    int ps = pg * 2 + qq;
    const unsigned short* srcA;
    if (tt < 7) {
      int j = fwd[ps * 7 + tt] / 7;
      srcA = xb + ((size_t)j * 4096 + mt * 256) * 64;
    } else {
      srcA = tb + (size_t)(mt * 256) * 64;
    }
    char* da = smem + buf * 32768;         // 32 KB: 512 thr x 16 B x 4
#pragma unroll
    for (int i = 0; i < 4; ++i)
      gload16(srcA + tid * 8 + i * 4096, da + tid * 16 + i * 8192);
    const unsigned short* srcB = bmat + ((size_t)(ps * 8 + tt)) * 4096;
    gload16(srcB + tid * 8, smem + 65536 + buf * 8192 + tid * 16);  // 8 KB (R7-proven)
  };

  fx4 acc[2][2][4] = {};
  stage(0, 0);
#pragma unroll
  for (int q = 0; q < 2; ++q) {            // acc[q] statically indexed
#pragma unroll 1
    for (int t = 0; t < 8; ++t) {
      int s = q * 8 + t;
      __syncthreads();                     // stage(s) complete; prev-buf reads done
      if (s < 15) stage(s + 1, (s + 1) & 1);
      const char* ab = smem + (s & 1) * 32768;
      const char* bb = smem + 65536 + (s & 1) * 8192;
#pragma unroll
      for (int kk = 0; kk < 2; ++kk) {
        bfx8 bfr[4];
#pragma unroll
        for (int ni = 0; ni < 4; ++ni)
          bfr[ni] = *(const bfx8*)(bb + swzb(ni * 16 + lr, kk * 64 + lkb));
#pragma unroll
        for (int mi = 0; mi < 2; ++mi) {
          bfx8 af = *(const bfx8*)(ab + swzb(w * 32 + mi * 16 + lr, kk * 64 + lkb));
#pragma unroll
          for (int ni = 0; ni < 4; ++ni)
            acc[q][mi][ni] =
                __builtin_amdgcn_mfma_f32_16x16x32_bf16(af, bfr[ni], acc[q][mi][ni], 0, 0, 0);
        }
      }
    }
  }

  // Epilogue: 256 rows x 128 contiguous cols (pg*128 .. pg*128+127).
  size_t rbase = (size_t)(mt * 256 + w * 32) * 4096 + pg * 128;
#pragma unroll
  for (int q = 0; q < 2; ++q)
#pragma unroll
    for (int mi = 0; mi < 2; ++mi)
#pragma unroll
      for (int ni = 0; ni < 4; ++ni)
#pragma unroll
        for (int r = 0; r < 4; ++r)
          out[rbase + (size_t)(mi * 16 + (lane >> 4) * 4 + r) * 4096 + q * 64 + ni * 16 + lr] =
              acc[q][mi][ni][r];
}

// ---------------------------------------------------------------------------
// Fallback (ws tiny): naive fp32, correct but slow.
// ---------------------------------------------------------------------------
__global__ void naive_t_kern(const float* __restrict__ x, const float* __restrict__ w1,
                             float* __restrict__ t) {
  int gid = blockIdx.x * 256 + threadIdx.x;
  int b = gid >> 6, r = gid & 63;
  const float* xr = x + (size_t)b * 4096;
  const float* wr = w1 + (size_t)r * 4096;
  float s = 0.f;
  for (int k = 0; k < 4096; ++k) s += xr[k] * wr[k];
  t[gid] = s;
}

__global__ void naive_out_kern(const float* __restrict__ x, const float* __restrict__ weight,
                               const float* __restrict__ w2, const int* __restrict__ fwd,
                               const float* __restrict__ t, float* __restrict__ out) {
  size_t gid = (size_t)blockIdx.x * 256 + threadIdx.x;
  int b = (int)(gid >> 12), o = (int)(gid & 4095);
  int p = o >> 6, n = o & 63;
  float s = 0.f;
  for (int si = 0; si < 7; ++si) {
    int idx = fwd[p * 7 + si], j = idx / 7, a = idx - j * 7;
    const float* xr = x + (size_t)b * 4096 + j * 64;
    for (int k = 0; k < 64; ++k)
      s += xr[k] * weight[((size_t)(j * 64 + k) * 7 + a) * 64 + n];
  }
  const float* tr = t + (size_t)b * 64;
  const float* w2r = w2 + (size_t)o * 64;
  for (int r = 0; r < 64; ++r) s += tr[r] * w2r[r];
  out[gid] = s;
}

// ---------------------------------------------------------------------------
extern "C" void kernel_launch(void* const* d_in, const int* in_sizes, int n_in,
                              void* d_out, int out_size, void* d_ws, size_t ws_size,
                              hipStream_t stream) {
  const float* x = (const float*)d_in[0];
  const float* weight = (const float*)d_in[1];
  const float* w1 = (const float*)d_in[2];
  const float* w2 = (const float*)d_in[3];
  const int* fwd = (const int*)d_in[4];
  float* out = (float*)d_out;

  const size_t XB_E = 16777216;   // 64 * 4096 * 64
  const size_t TB_E = 262144;     // 4096 * 64
  const size_t BM_E = 2097152;    // 64 * 8 * 64 * 64
  const size_t W1_E = 262144;     // 64 * 64 * 64
  const size_t BASE_B = (XB_E + TB_E + BM_E + W1_E) * 2;  // 38797312 B (proven available)

  if (ws_size >= BASE_B) {
    unsigned short* xb = (unsigned short*)d_ws;
    unsigned short* tb = xb + XB_E;
    unsigned short* bmat = tb + TB_E;
    unsigned short* w1b = bmat + BM_E;
    float* part = out;                       // 8 MB scratch inside d_out
    int* cnt = (int*)((char*)d_out + (32u << 20));  // 64 ints at out+32MB (outside part;
                                                    // butterfly overwrites all of out later)
    hipMemsetAsync(cnt, 0, 64 * sizeof(int), stream);  // deterministic reset per call
    prep_all_kern<<<8768, 256, 0, stream>>>(weight, w1, w2, fwd, x, bmat, w1b, xb);
    compute_t_fused<<<512, 256, 0, stream>>>(xb, w1b, part, tb, cnt);
    butterfly_mp5<<<512, 512, 0, stream>>>(xb, tb, bmat, fwd, out);
  } else {
    float* t = (float*)d_ws;
    naive_t_kern<<<1024, 256, 0, stream>>>(x, w1, t);
    naive_out_kern<<<65536, 256, 0, stream>>>(x, weight, w2, fwd, t, out);
  }
}

// Round 17
// 63.613 us; speedup vs baseline: 2.2126x; 2.2126x over previous
//
#include <hip/hip_runtime.h>
#include <hip/hip_bf16.h>

// Problem constants
//   x:   [4096, 4096] f32
//   w:   [4096, 7, 64] f32   (weight[j*64+k][a][n])
//   w1:  [64, 4096] f32      (lowrank_first)
//   w2:  [4096, 64] f32      (lowrank_second)
//   fwd: [64, 7] i32         (forward_indices; idx = j*7 + a)
//   out: [4096, 4096] f32
//
// out block p = sum_s x[:, j_s*64:+64] @ w[j_s,:,a_s,:]  +  T @ W2_p^T
// with T = x @ w1^T.  Per p: GEMM [4096,512] x [512,64].
// FINAL BUILD = round-13/15 best (63.6-63.8 us, reproduced twice), restored
// after the R16 last-wg-fixup fusion regressed 2.2x (device-scope
// __threadfence x512 wgs = cross-XCD L2 writeback storm; G16 lesson).

#define DEVINL __device__ __forceinline__

typedef __attribute__((ext_vector_type(8))) short bfx8;   // 8 bf16 (4 VGPRs)
typedef __attribute__((ext_vector_type(4))) float fx4;

DEVINL short f2bf(float f) {   // round-to-nearest-even f32 -> bf16 bits
  unsigned u = __builtin_bit_cast(unsigned, f);
  unsigned r = 0x7FFFu + ((u >> 16) & 1u);
  return (short)((u + r) >> 16);
}

// XOR swizzle: tiles are [rows][64 cols] bf16, row stride 128 B.
// byte offset = row*128 + (colbyte ^ ((row&7)<<4))  -> ds_read_b128 conflict-free.
DEVINL int swzb(int row, int kbyte) { return (row << 7) + (kbyte ^ ((row & 7) << 4)); }

DEVINL void gload16(const void* g, void* l) {
  __builtin_amdgcn_global_load_lds(
      (const __attribute__((address_space(1))) unsigned int*)g,
      (__attribute__((address_space(3))) unsigned int*)l, 16, 0, 0);
}

// ---------------------------------------------------------------------------
// P0 (merged): blocks 0..575 = prep_b; blocks 576..8767 = convert_x.
// (proven round-7 kernel, verbatim)
// ---------------------------------------------------------------------------
__global__ __launch_bounds__(256) void prep_all_kern(
    const float* __restrict__ weight, const float* __restrict__ w1,
    const float* __restrict__ w2, const int* __restrict__ fwd,
    const float* __restrict__ x, unsigned short* __restrict__ bmat,
    unsigned short* __restrict__ w1b, unsigned short* __restrict__ xb) {
  int cid = blockIdx.x, tid = threadIdx.x;
  if (cid >= 576) {
    int gid = (cid - 576) * 256 + tid;
    int b = gid >> 9, c8 = gid & 511;
    int j = c8 >> 3, c0 = (c8 & 7) << 3;
    const float* src = x + (size_t)b * 4096 + j * 64 + c0;
    fx4 v0 = *(const fx4*)src;
    fx4 v1 = *(const fx4*)(src + 4);
    bfx8 o;
    o[0] = f2bf(v0[0]); o[1] = f2bf(v0[1]); o[2] = f2bf(v0[2]); o[3] = f2bf(v0[3]);
    o[4] = f2bf(v1[0]); o[5] = f2bf(v1[1]); o[6] = f2bf(v1[2]); o[7] = f2bf(v1[3]);
    size_t off = (size_t)j * 262144 + (size_t)b * 64 + ((((c0 << 1) ^ ((b & 7) << 4))) >> 1);
    *(bfx8*)(xb + off) = o;
    return;
  }
  if (cid < 512) {
    int p = cid >> 3, t = cid & 7;
    unsigned short* dst = bmat + (size_t)cid * 4096;
    if (t < 7) {
      int idx = fwd[p * 7 + t];
      int j = idx / 7, a = idx - j * 7;
      int k = tid >> 2, n0 = (tid & 3) << 4;
      const float* src = weight + ((size_t)(j * 64 + k) * 7 + a) * 64 + n0;
#pragma unroll
      for (int e = 0; e < 16; ++e) {
        int n = n0 + e;
        dst[(n << 6) + ((((k << 1) ^ ((n & 7) << 4))) >> 1)] = f2bf(src[e]);
      }
    } else {
      int n = tid >> 2, r0 = (tid & 3) << 4;
      const float* src = w2 + ((size_t)(p * 64 + n)) * 64 + r0;
#pragma unroll
      for (int e = 0; e < 16; ++e) {
        int k = r0 + e;
        dst[(n << 6) + ((((k << 1) ^ ((n & 7) << 4))) >> 1)] = f2bf(src[e]);
      }
    }
  } else {
    int jc = cid - 512;
    unsigned short* dst = w1b + (size_t)jc * 4096;
    int r = tid >> 2, k0 = (tid & 3) << 4;
    const float* src = w1 + (size_t)r * 4096 + jc * 64 + k0;
#pragma unroll
    for (int e = 0; e < 16; ++e) {
      int k = k0 + e;
      dst[(r << 6) + ((((k << 1) ^ ((r & 7) << 4))) >> 1)] = f2bf(src[e]);
    }
  }
}

// ---------------------------------------------------------------------------
// P1b: split-K T-partials. 512 wgs = 64 row-tiles(64) x 8 K-chunks.
//      (proven, verbatim; part lives in d_out)
// ---------------------------------------------------------------------------
__global__ __launch_bounds__(256) void compute_t_split(const unsigned short* __restrict__ xb,
                                                       const unsigned short* __restrict__ w1b,
                                                       float* __restrict__ part) {
  __shared__ char smem[32768];
  int rt = blockIdx.x >> 3, kc = blockIdx.x & 7;
  int tid = threadIdx.x, lane = tid & 63, w = tid >> 6;
  int lr = lane & 15, lkb = (lane >> 4) << 4;

  auto stage = [&](int jc, int buf) {
    const unsigned short* sa = xb + (size_t)(kc * 8 + jc) * 262144 + (size_t)rt * 4096;
    const unsigned short* sb = w1b + (size_t)(kc * 8 + jc) * 4096;
    char* da = smem + buf * 8192;
    char* db = smem + 16384 + buf * 8192;
#pragma unroll
    for (int i = 0; i < 2; ++i) {
      gload16(sa + tid * 8 + i * 2048, da + tid * 16 + i * 4096);
      gload16(sb + tid * 8 + i * 2048, db + tid * 16 + i * 4096);
    }
  };

  fx4 acc[4] = {};
  stage(0, 0);
#pragma unroll 1
  for (int jc = 0; jc < 8; ++jc) {
    __syncthreads();
    int cur = jc & 1;
    if (jc < 7) stage(jc + 1, cur ^ 1);
    const char* ab = smem + cur * 8192;
    const char* bb = smem + 16384 + cur * 8192;
#pragma unroll
    for (int kk = 0; kk < 2; ++kk) {
      bfx8 af = *(const bfx8*)(ab + swzb(w * 16 + lr, kk * 64 + lkb));
#pragma unroll
      for (int ni = 0; ni < 4; ++ni) {
        bfx8 bf = *(const bfx8*)(bb + swzb(ni * 16 + lr, kk * 64 + lkb));
        acc[ni] = __builtin_amdgcn_mfma_f32_16x16x32_bf16(af, bf, acc[ni], 0, 0, 0);
      }
    }
  }
  float* pb = part + (size_t)kc * 262144 + (size_t)rt * 4096;
#pragma unroll
  for (int ni = 0; ni < 4; ++ni)
#pragma unroll
    for (int r = 0; r < 4; ++r) {
      int row = w * 16 + (lane >> 4) * 4 + r;
      pb[(size_t)row * 64 + ni * 16 + lr] = acc[ni][r];
    }
}

// ---------------------------------------------------------------------------
// P1c: reduce 8 T-partials -> tb bf16 pre-swizzled. (proven, verbatim)
// ---------------------------------------------------------------------------
__global__ __launch_bounds__(256) void reduce_t_kern(const float* __restrict__ part,
                                                     unsigned short* __restrict__ tb) {
  int gid = blockIdx.x * 256 + threadIdx.x;   // 32768 threads: 4096 rows x 8 col-groups
  int b = gid >> 3, c0 = (gid & 7) << 3;
  const float* pp = part + (size_t)b * 64 + c0;
  fx4 s0 = {0.f, 0.f, 0.f, 0.f}, s1 = {0.f, 0.f, 0.f, 0.f};
#pragma unroll
  for (int kc = 0; kc < 8; ++kc) {
    s0 += *(const fx4*)(pp + (size_t)kc * 262144);
    s1 += *(const fx4*)(pp + (size_t)kc * 262144 + 4);
  }
  bfx8 o;
#pragma unroll
  for (int e = 0; e < 4; ++e) { o[e] = f2bf(s0[e]); o[e + 4] = f2bf(s1[e]); }
  *(bfx8*)(tb + (size_t)b * 64 + ((((c0 << 1) ^ ((b & 7) << 4))) >> 1)) = o;
}

// ---------------------------------------------------------------------------
// P2: multi-p butterfly GEMM, 256-row tiles. 512 wgs = 16 mt x 32 pg
// (2 adjacent p per wg). 512 thr (8 waves), wave = 32 rows,
// acc[2 q][2 mi][4 ni] statically indexed. 16 stage steps s = q*8+t.
// Staged bytes: 320 MB (min achievable within LDS). LDS: A dbuf 2x32K @0;
// B dbuf 2x8K @65536 = 80 KB -> 2 wg/CU = 16 waves/CU (measured optimum:
// 24 waves regressed R14; pipelining neutral R5/R9/R10; barrier cadence
// neutral R9; B-residency slower R11). Coarse 512B-strip epilogue.
// (proven round-13 kernel, verbatim)
// ---------------------------------------------------------------------------
__global__ __launch_bounds__(512, 2) void butterfly_mp5(
    const unsigned short* __restrict__ xb, const unsigned short* __restrict__ tb,
    const unsigned short* __restrict__ bmat, const int* __restrict__ fwd,
    float* __restrict__ out) {
  __shared__ char smem[81920];   // A dbuf 2x32K @0; B dbuf 2x8K @65536
  int bid = blockIdx.x;
  int wid = (bid & 7) * 64 + (bid >> 3);   // bijective XCD swizzle (512 % 8 == 0)
  int mt = wid >> 5, pg = wid & 31;        // pg fastest within an XCD chunk
  int tid = threadIdx.x, lane = tid & 63, w = tid >> 6;
  int lr = lane & 15, lkb = (lane >> 4) << 4;

  auto stage = [&](int s, int buf) {       // s = q*8 + t
    int qq = s >> 3, tt = s & 7;
    int ps = pg * 2 + qq;
    const unsigned short* srcA;
    if (tt < 7) {
      int j = fwd[ps * 7 + tt] / 7;
      srcA = xb + ((size_t)j * 4096 + mt * 256) * 64;
    } else {
      srcA = tb + (size_t)(mt * 256) * 64;
    }
    char* da = smem + buf * 32768;         // 32 KB: 512 thr x 16 B x 4
#pragma unroll
    for (int i = 0; i < 4; ++i)
      gload16(srcA + tid * 8 + i * 4096, da + tid * 16 + i * 8192);
    const unsigned short* srcB = bmat + ((size_t)(ps * 8 + tt)) * 4096;
    gload16(srcB + tid * 8, smem + 65536 + buf * 8192 + tid * 16);  // 8 KB (R7-proven)
  };

  fx4 acc[2][2][4] = {};
  stage(0, 0);
#pragma unroll
  for (int q = 0; q < 2; ++q) {            // acc[q] statically indexed
#pragma unroll 1
    for (int t = 0; t < 8; ++t) {
      int s = q * 8 + t;
      __syncthreads();                     // stage(s) complete; prev-buf reads done
      if (s < 15) stage(s + 1, (s + 1) & 1);
      const char* ab = smem + (s & 1) * 32768;
      const char* bb = smem + 65536 + (s & 1) * 8192;
#pragma unroll
      for (int kk = 0; kk < 2; ++kk) {
        bfx8 bfr[4];
#pragma unroll
        for (int ni = 0; ni < 4; ++ni)
          bfr[ni] = *(const bfx8*)(bb + swzb(ni * 16 + lr, kk * 64 + lkb));
#pragma unroll
        for (int mi = 0; mi < 2; ++mi) {
          bfx8 af = *(const bfx8*)(ab + swzb(w * 32 + mi * 16 + lr, kk * 64 + lkb));
#pragma unroll
          for (int ni = 0; ni < 4; ++ni)
            acc[q][mi][ni] =
                __builtin_amdgcn_mfma_f32_16x16x32_bf16(af, bfr[ni], acc[q][mi][ni], 0, 0, 0);
        }
      }
    }
  }

  // Epilogue: 256 rows x 128 contiguous cols (pg*128 .. pg*128+127).
  size_t rbase = (size_t)(mt * 256 + w * 32) * 4096 + pg * 128;
#pragma unroll
  for (int q = 0; q < 2; ++q)
#pragma unroll
    for (int mi = 0; mi < 2; ++mi)
#pragma unroll
      for (int ni = 0; ni < 4; ++ni)
#pragma unroll
        for (int r = 0; r < 4; ++r)
          out[rbase + (size_t)(mi * 16 + (lane >> 4) * 4 + r) * 4096 + q * 64 + ni * 16 + lr] =
              acc[q][mi][ni][r];
}

// ---------------------------------------------------------------------------
// Fallback (ws tiny): naive fp32, correct but slow.
// ---------------------------------------------------------------------------
__global__ void naive_t_kern(const float* __restrict__ x, const float* __restrict__ w1,
                             float* __restrict__ t) {
  int gid = blockIdx.x * 256 + threadIdx.x;
  int b = gid >> 6, r = gid & 63;
  const float* xr = x + (size_t)b * 4096;
  const float* wr = w1 + (size_t)r * 4096;
  float s = 0.f;
  for (int k = 0; k < 4096; ++k) s += xr[k] * wr[k];
  t[gid] = s;
}

__global__ void naive_out_kern(const float* __restrict__ x, const float* __restrict__ weight,
                               const float* __restrict__ w2, const int* __restrict__ fwd,
                               const float* __restrict__ t, float* __restrict__ out) {
  size_t gid = (size_t)blockIdx.x * 256 + threadIdx.x;
  int b = (int)(gid >> 12), o = (int)(gid & 4095);
  int p = o >> 6, n = o & 63;
  float s = 0.f;
  for (int si = 0; si < 7; ++si) {
    int idx = fwd[p * 7 + si], j = idx / 7, a = idx - j * 7;
    const float* xr = x + (size_t)b * 4096 + j * 64;
    for (int k = 0; k < 64; ++k)
      s += xr[k] * weight[((size_t)(j * 64 + k) * 7 + a) * 64 + n];
  }
  const float* tr = t + (size_t)b * 64;
  const float* w2r = w2 + (size_t)o * 64;
  for (int r = 0; r < 64; ++r) s += tr[r] * w2r[r];
  out[gid] = s;
}

// ---------------------------------------------------------------------------
extern "C" void kernel_launch(void* const* d_in, const int* in_sizes, int n_in,
                              void* d_out, int out_size, void* d_ws, size_t ws_size,
                              hipStream_t stream) {
  const float* x = (const float*)d_in[0];
  const float* weight = (const float*)d_in[1];
  const float* w1 = (const float*)d_in[2];
  const float* w2 = (const float*)d_in[3];
  const int* fwd = (const int*)d_in[4];
  float* out = (float*)d_out;

  const size_t XB_E = 16777216;   // 64 * 4096 * 64
  const size_t TB_E = 262144;     // 4096 * 64
  const size_t BM_E = 2097152;    // 64 * 8 * 64 * 64
  const size_t W1_E = 262144;     // 64 * 64 * 64
  const size_t BASE_B = (XB_E + TB_E + BM_E + W1_E) * 2;  // 38797312 B (proven available)

  if (ws_size >= BASE_B) {
    unsigned short* xb = (unsigned short*)d_ws;
    unsigned short* tb = xb + XB_E;
    unsigned short* bmat = tb + TB_E;
    unsigned short* w1b = bmat + BM_E;
    float* part = out;  // 8 MB scratch inside d_out; fully overwritten by butterfly
    prep_all_kern<<<8768, 256, 0, stream>>>(weight, w1, w2, fwd, x, bmat, w1b, xb);
    compute_t_split<<<512, 256, 0, stream>>>(xb, w1b, part);
    reduce_t_kern<<<128, 256, 0, stream>>>(part, tb);
    butterfly_mp5<<<512, 512, 0, stream>>>(xb, tb, bmat, fwd, out);
  } else {
    float* t = (float*)d_ws;
    naive_t_kern<<<1024, 256, 0, stream>>>(x, w1, t);
    naive_out_kern<<<65536, 256, 0, stream>>>(x, weight, w2, fwd, t, out);
  }
}